// Round 6
// baseline (1351.562 us; speedup 1.0000x reference)
//
#include <hip/hip_runtime.h>

constexpr int TT = 512;    // timesteps
constexpr int BB = 256;    // batch
constexpr int HH = 128;    // hidden = embed
constexpr int VV = 32000;  // vocab
constexpr int MB = 16;     // batch rows per block (MFMA M tile)

typedef _Float16 h2 __attribute__((ext_vector_type(2)));
typedef _Float16 f16x4 __attribute__((ext_vector_type(4)));
typedef _Float16 f16x8 __attribute__((ext_vector_type(8)));
typedef float f32x4 __attribute__((ext_vector_type(4)));

struct __align__(16) H2x4 { h2 a, b, c, d; };

__device__ __forceinline__ h2 pkrtz(float a, float b) {
  return __builtin_bit_cast(h2, __builtin_amdgcn_cvt_pkrtz(a, b));
}
__device__ __forceinline__ float fdot2(h2 a, h2 b, float c) {
  return __builtin_amdgcn_fdot2(a, b, c, false);
}
__device__ __forceinline__ float fsigmoid(float x) {
  return 1.f / (1.f + __expf(-x));
}
__device__ __forceinline__ float ftanh(float x) {
  return 1.f - 2.f / (__expf(2.f * x) + 1.f);
}

// Pre-gather embeddings into MFMA B-fragment layout, f16:
// xe[bx][t][kt][lane][j] = emb[ x[bx*16 + (lane&15)][t] ][ kt*32 + (lane>>4)*8 + j ]
// One thread per f16x8 chunk; 2.1M chunks.
__global__ __launch_bounds__(256, 4) void xe_pre(const int* __restrict__ x,
                                                 const float* __restrict__ emb,
                                                 _Float16* __restrict__ xe) {
  const int id = blockIdx.x * 256 + threadIdx.x;
  const int lane = id & 63;
  const int kt = (id >> 6) & 3;
  const int t = (id >> 8) & 511;
  const int bx = id >> 17;
  const int m = lane & 15;
  const int k0 = kt * 32 + (lane >> 4) * 8;
  const int tok = x[(bx * MB + m) * TT + t];
  const float4 a = *(const float4*)(emb + (size_t)tok * HH + k0);
  const float4 b = *(const float4*)(emb + (size_t)tok * HH + k0 + 4);
  H2x4 q;
  q.a = pkrtz(a.x, a.y);
  q.b = pkrtz(a.z, a.w);
  q.c = pkrtz(b.x, b.y);
  q.d = pkrtz(b.z, b.w);
  *(H2x4*)(xe + (size_t)id * 8) = q;
}

// 16 blocks x 1024 threads (16 waves, 4/SIMD -> 128-reg cap so weights stay
// in arch VGPRs; acc lives in AGPRs natively).
// K-split by source: e-waves (0..7) own k=0..127, B-operand streamed from
// global xe (pre-swizzled fragments, prefetched one step ahead, zero LDS).
// h-waves (8..15) own k=128..255, B-operand = h from 4KB double-buffered LDS.
// Wave w handles unit group ug=w&7: n-tiles {ug,ug+8,ug+16,ug+24} = all 4
// gates of units [16ug,16ug+16) -> 4 gates x 4 k-tiles = 64 weight VGPRs.
// h-waves pack partial pre-activations to f16 (2 conflict-free b128 to LDS);
// e-waves v_dot2-reduce (fp32 accumulate), activate in-lane (D: col=lane&15
// = batch, row=quad*4+r = unit), c-state in regs, write h to other buffer.
// Two barriers per step.
__global__ __launch_bounds__(1024, 4) void lstm_rec(
    const float* __restrict__ Wi, const float* __restrict__ bi,
    const float* __restrict__ Wf, const float* __restrict__ bf,
    const float* __restrict__ Wc, const float* __restrict__ bc,
    const float* __restrict__ Wo, const float* __restrict__ bo,
    const _Float16* __restrict__ xe, _Float16* __restrict__ hbf) {
  const int tid = threadIdx.x;
  const int w = tid >> 6;      // wave 0..15
  const int lane = tid & 63;
  const int m16 = lane & 15;
  const int quad = lane >> 4;
  const int ug = w & 7;
  const bool ew = (w < 8);     // e-wave?
  const int B0 = blockIdx.x * MB;

  __shared__ __align__(16) _Float16 combh[2 * 2048];     // h frags, 2 x 4KB
  __shared__ __align__(16) _Float16 part[2 * 8 * 64 * 8]; // partA | partB

  // ---- weight fragments: n-col = 16*ug + m16, k = (ktbase+kt2)*32 + quad*8 + j
  const float* Wp[4] = {Wi, Wf, Wc, Wo};
  const int ncol = 16 * ug + m16;
  const int ktbase = ew ? 0 : 4;
  f16x8 wfrag[4][4];
#pragma unroll
  for (int g = 0; g < 4; ++g) {
    const float* Wg = Wp[g];
#pragma unroll
    for (int kt2 = 0; kt2 < 4; ++kt2) {
      const float* base = Wg + (size_t)((ktbase + kt2) * 32 + quad * 8) * HH + ncol;
      f16x8 v;
#pragma unroll
      for (int j = 0; j < 8; ++j) v[j] = (_Float16)base[j * HH];
      wfrag[g][kt2] = v;
    }
  }

  // e-wave state: biases + c-state for units u0..u0+3, batch m16
  const int u0 = 16 * ug + 4 * quad;
  float bia[4] = {}, bif[4] = {}, bic[4] = {}, bio[4] = {};
  if (ew) {
#pragma unroll
    for (int r = 0; r < 4; ++r) {
      bia[r] = bi[u0 + r]; bif[r] = bf[u0 + r];
      bic[r] = bc[u0 + r]; bio[r] = bo[u0 + r];
    }
  }
  float cst[4] = {0.f, 0.f, 0.f, 0.f};

  // h-write offset into combh buffer (k' = u0 within 128-wide h region)
  const int hoff = (u0 >> 5) * 512 + (m16 + 16 * ((u0 >> 3) & 3)) * 8 + (u0 & 7);
  // partial-exchange offset (16B per lane, conflict-free)
  const int poff = (ug * 64 + lane) * 8;
  constexpr int PB = 8 * 64 * 8;  // partB offset

  // per-block xe stream: 2048 f16 per step
  const _Float16* xeb = xe + (size_t)blockIdx.x * TT * 2048;

  // init: combh buf0 = h_0 = 0
  if (tid < 256) {
    f16x8 z = {};
    *(f16x8*)(combh + tid * 8) = z;
  }
  f16x8 efrag[4];
  if (ew) {
#pragma unroll
    for (int kt2 = 0; kt2 < 4; ++kt2)
      efrag[kt2] = *(const f16x8*)(xeb + kt2 * 512 + lane * 8);
  }
  __syncthreads();

  const h2 LO = h2{(_Float16)1.f, (_Float16)0.f};
  const h2 HI = h2{(_Float16)0.f, (_Float16)1.f};

  int buf = 0;
  for (int t = 0; t < TT; ++t) {
    f32x4 acc[4] = {{0, 0, 0, 0}, {0, 0, 0, 0}, {0, 0, 0, 0}, {0, 0, 0, 0}};
    if (ew) {
      // ---- e-waves: MFMA over k=0..127 with prefetched global fragments
#pragma unroll
      for (int kt2 = 0; kt2 < 4; ++kt2) {
#pragma unroll
        for (int g = 0; g < 4; ++g)
          acc[g] = __builtin_amdgcn_mfma_f32_16x16x32_f16(wfrag[g][kt2],
                                                          efrag[kt2], acc[g],
                                                          0, 0, 0);
      }
    } else {
      // ---- h-waves: MFMA over k=128..255 with LDS h fragments
      f16x8 bfrag[4];
      const _Float16* cb = combh + buf * 2048 + lane * 8;
#pragma unroll
      for (int kt2 = 0; kt2 < 4; ++kt2)
        bfrag[kt2] = *(const f16x8*)(cb + kt2 * 512);
#pragma unroll
      for (int kt2 = 0; kt2 < 4; ++kt2) {
#pragma unroll
        for (int g = 0; g < 4; ++g)
          acc[g] = __builtin_amdgcn_mfma_f32_16x16x32_f16(wfrag[g][kt2],
                                                          bfrag[kt2], acc[g],
                                                          0, 0, 0);
      }
      // pack partials (f16, values ~O(0.1): rounding ~1e-4 abs) and export
      H2x4 qa, qb;
      qa.a = pkrtz(acc[0][0], acc[0][1]);
      qa.b = pkrtz(acc[0][2], acc[0][3]);
      qa.c = pkrtz(acc[1][0], acc[1][1]);
      qa.d = pkrtz(acc[1][2], acc[1][3]);
      qb.a = pkrtz(acc[2][0], acc[2][1]);
      qb.b = pkrtz(acc[2][2], acc[2][3]);
      qb.c = pkrtz(acc[3][0], acc[3][1]);
      qb.d = pkrtz(acc[3][2], acc[3][3]);
      *(H2x4*)(part + poff) = qa;
      *(H2x4*)(part + PB + poff) = qb;
    }
    __syncthreads();  // A: partials visible

    if (ew) {
      const H2x4 pa = *(const H2x4*)(part + poff);
      const H2x4 pb = *(const H2x4*)(part + PB + poff);
      float ai0 = fdot2(pa.a, LO, acc[0][0]);
      float ai1 = fdot2(pa.a, HI, acc[0][1]);
      float ai2 = fdot2(pa.b, LO, acc[0][2]);
      float ai3 = fdot2(pa.b, HI, acc[0][3]);
      float af0 = fdot2(pa.c, LO, acc[1][0]);
      float af1 = fdot2(pa.c, HI, acc[1][1]);
      float af2 = fdot2(pa.d, LO, acc[1][2]);
      float af3 = fdot2(pa.d, HI, acc[1][3]);
      float ac0 = fdot2(pb.a, LO, acc[2][0]);
      float ac1 = fdot2(pb.a, HI, acc[2][1]);
      float ac2 = fdot2(pb.b, LO, acc[2][2]);
      float ac3 = fdot2(pb.b, HI, acc[2][3]);
      float ao0 = fdot2(pb.c, LO, acc[3][0]);
      float ao1 = fdot2(pb.c, HI, acc[3][1]);
      float ao2 = fdot2(pb.d, LO, acc[3][2]);
      float ao3 = fdot2(pb.d, HI, acc[3][3]);
      const float aiv[4] = {ai0, ai1, ai2, ai3};
      const float afv[4] = {af0, af1, af2, af3};
      const float acv[4] = {ac0, ac1, ac2, ac3};
      const float aov[4] = {ao0, ao1, ao2, ao3};
      f16x4 hv;
#pragma unroll
      for (int r = 0; r < 4; ++r) {
        const float gi = fsigmoid(aiv[r] + bia[r]);
        const float gf = fsigmoid(afv[r] + bif[r]);
        const float gc = ftanh(acv[r] + bic[r]);
        const float go = fsigmoid(aov[r] + bio[r]);
        cst[r] = gf * cst[r] + gi * gc;
        hv[r] = (_Float16)(go * ftanh(cst[r]));
      }
      *(f16x4*)(combh + (buf ^ 1) * 2048 + hoff) = hv;
      if (t == TT - 1)
        *(f16x4*)(hbf + (size_t)(B0 + m16) * HH + u0) = hv;
      // prefetch next step's e fragments (consumed after barrier B)
      const int tn = (t + 1 < TT) ? t + 1 : TT - 1;
      const _Float16* xet = xeb + (size_t)tn * 2048 + lane * 8;
#pragma unroll
      for (int kt2 = 0; kt2 < 4; ++kt2)
        efrag[kt2] = *(const f16x8*)(xet + kt2 * 512);
    }
    __syncthreads();  // B: combh[buf^1] complete
    buf ^= 1;
  }
}

// Wout[k][v] fp32 -> Wt[v][k] fp16 (coalesced loads across lanes=v).
__global__ __launch_bounds__(256, 4) void wout_tr(const float* __restrict__ Wout,
                                                  _Float16* __restrict__ Wt) {
  const int v = blockIdx.x * 256 + threadIdx.x;
#pragma unroll 1
  for (int kc = 0; kc < 16; ++kc) {
    float f[8];
#pragma unroll
    for (int i = 0; i < 8; ++i) f[i] = Wout[(size_t)(kc * 8 + i) * VV + v];
    H2x4 q;
    q.a = pkrtz(f[0], f[1]);
    q.b = pkrtz(f[2], f[3]);
    q.c = pkrtz(f[4], f[5]);
    q.d = pkrtz(f[6], f[7]);
    *(H2x4*)(Wt + (size_t)v * HH + kc * 8) = q;
  }
}

// logits = h @ Wout + bout via f16 MFMA, register-only.
// Block: 4 waves; tile [64 bat x 128 v]; wave: [64 bat x 32 v].
__global__ __launch_bounds__(256, 4) void lstm_out(
    const _Float16* __restrict__ Wt, const _Float16* __restrict__ hbf,
    const float* __restrict__ bout, float* __restrict__ out) {
  const int tid = threadIdx.x;
  const int wv = tid >> 6;
  const int lane = tid & 63;
  const int vblk = blockIdx.x % 250;
  const int batblk = blockIdx.x / 250;
  const int n16 = lane & 15;
  const int quad = lane >> 4;
  const int vbase = vblk * 128 + wv * 32;
  const int batbase = batblk * 64;

  f32x4 acc[4][2] = {};
#pragma unroll
  for (int ks = 0; ks < 4; ++ks) {
    const int k = ks * 32 + quad * 8;
    f16x8 a[4], bf_[2];
#pragma unroll
    for (int mt = 0; mt < 4; ++mt)
      a[mt] = *(const f16x8*)(hbf + (size_t)(batbase + mt * 16 + n16) * HH + k);
#pragma unroll
    for (int vt = 0; vt < 2; ++vt)
      bf_[vt] = *(const f16x8*)(Wt + (size_t)(vbase + vt * 16 + n16) * HH + k);
#pragma unroll
    for (int mt = 0; mt < 4; ++mt)
#pragma unroll
      for (int vt = 0; vt < 2; ++vt)
        acc[mt][vt] = __builtin_amdgcn_mfma_f32_16x16x32_f16(a[mt], bf_[vt],
                                                             acc[mt][vt], 0, 0, 0);
  }
#pragma unroll
  for (int vt = 0; vt < 2; ++vt) {
    const int v = vbase + vt * 16 + n16;
    const float bv = bout[v];
#pragma unroll
    for (int mt = 0; mt < 4; ++mt) {
#pragma unroll
      for (int r = 0; r < 4; ++r) {
        const int bat = batbase + mt * 16 + quad * 4 + r;
        out[(size_t)bat * VV + v] = acc[mt][vt][r] + bv;
      }
    }
  }
}

extern "C" void kernel_launch(void* const* d_in, const int* in_sizes, int n_in,
                              void* d_out, int out_size, void* d_ws,
                              size_t ws_size, hipStream_t stream) {
  const int* x = (const int*)d_in[0];
  const float* emb = (const float*)d_in[1];
  const float* Wi = (const float*)d_in[2];
  const float* bi = (const float*)d_in[3];
  const float* Wf = (const float*)d_in[4];
  const float* bf = (const float*)d_in[5];
  const float* Wc = (const float*)d_in[6];
  const float* bc = (const float*)d_in[7];
  const float* Wo = (const float*)d_in[8];
  const float* bo = (const float*)d_in[9];
  const float* Wout = (const float*)d_in[10];
  const float* bout = (const float*)d_in[11];
  float* out = (float*)d_out;

  _Float16* Wt = (_Float16*)d_ws;          // 32000*128 f16 = 8.192 MB
  _Float16* hbf = Wt + (size_t)VV * HH;    // 256*128 f16 = 64 KB
  _Float16* xe = hbf + (size_t)BB * HH;    // 16*512*2048 f16 = 33.5 MB

  xe_pre<<<(MB == 16 ? 8192 : 8192), 256, 0, stream>>>(x, emb, xe);
  lstm_rec<<<BB / MB, 1024, 0, stream>>>(Wi, bi, Wf, bf, Wc, bc, Wo, bo, xe,
                                         hbf);
  wout_tr<<<VV / 256, 256, 0, stream>>>(Wout, Wt);
  lstm_out<<<(VV / 128) * (BB / 64), 256, 0, stream>>>(Wt, hbf, bout, out);
}

// Round 8
// 647.281 us; speedup vs baseline: 2.0881x; 2.0881x over previous
//
#include <hip/hip_runtime.h>

constexpr int TT = 512;    // timesteps
constexpr int BB = 256;    // batch
constexpr int HH = 128;    // hidden = embed
constexpr int VV = 32000;  // vocab

typedef _Float16 h2 __attribute__((ext_vector_type(2)));
typedef _Float16 f16x4 __attribute__((ext_vector_type(4)));
typedef _Float16 f16x8 __attribute__((ext_vector_type(8)));
typedef float f32x4 __attribute__((ext_vector_type(4)));

struct __align__(16) H2x4 { h2 a, b, c, d; };

__device__ __forceinline__ h2 pkrtz(float a, float b) {
  return __builtin_bit_cast(h2, __builtin_amdgcn_cvt_pkrtz(a, b));
}
__device__ __forceinline__ float fdot2(h2 a, h2 b, float c) {
  return __builtin_amdgcn_fdot2(a, b, c, false);
}
__device__ __forceinline__ float fsigmoid(float x) {
  return 1.f / (1.f + __expf(-x));
}
__device__ __forceinline__ float ftanh(float x) {
  return 1.f - 2.f / (__expf(2.f * x) + 1.f);
}

// One block per batch element (256 blocks = 256 CUs), 512 threads = 8 waves.
// R1 regime (proven clean: launch_bounds(512,2), ~140 VGPRs, dot2-only) with
// the comb LDS traffic k-split 8x:
//   wave w = k-slice [32w, 32w+32); lane l = units {2l, 2l+1} x 4 gates.
//   comb read: 4 wave-uniform ds_read_b128 per thread (32/CU-step vs R1's 256)
//   weights: 8 outputs x 16 h2 = 128 VGPRs (R1's exact budget)
//   partials: f16x8 pack -> 1 conflict-free b128/thread
//   reducers (tid<128, waves 0-1): 8x f16x4 reads at 4u (contiguous 8B/lane),
//   fp32 fdot2 reduce, activation + c-state in regs, h + prefetched e ->
//   double-buffered comb.
// 2 barriers/step; emb gather issued a full phase before its use.
__global__ __launch_bounds__(512, 2) void lstm_rec(
    const int* __restrict__ x, const float* __restrict__ emb,
    const float* __restrict__ Wi, const float* __restrict__ bi,
    const float* __restrict__ Wf, const float* __restrict__ bf,
    const float* __restrict__ Wc, const float* __restrict__ bc,
    const float* __restrict__ Wo, const float* __restrict__ bo,
    _Float16* __restrict__ hbf) {
  const int b = blockIdx.x;
  const int tid = threadIdx.x;
  const int w = tid >> 6;   // k-slice 0..7
  const int l = tid & 63;   // unit pair

  __shared__ int xrow[TT];
  __shared__ __align__(16) _Float16 comb[2][256];    // [buf][k] f16 (e|h)
  __shared__ __align__(16) _Float16 part[8][64][8];  // [slice][pair][8 gates]

  xrow[tid & (TT - 1)] = x[b * TT + (tid & (TT - 1))];

  // ---- weights: wfr[g][j][i] = {Wg[k0+2i][2l+j], Wg[k0+2i+1][2l+j]}, k0=32w
  // float2 loads are fully lane-coalesced (lane l -> cols 2l,2l+1).
  const float* Wp[4] = {Wi, Wf, Wc, Wo};
  h2 wfr[4][2][16];
#pragma unroll
  for (int g = 0; g < 4; ++g) {
    const float* Wg = Wp[g];
#pragma unroll
    for (int i = 0; i < 16; ++i) {
      const int k0 = 32 * w + 2 * i;
      const float2 r0 = *(const float2*)(Wg + (size_t)k0 * HH + 2 * l);
      const float2 r1 = *(const float2*)(Wg + (size_t)(k0 + 1) * HH + 2 * l);
      wfr[g][0][i] = h2{(_Float16)r0.x, (_Float16)r1.x};
      wfr[g][1][i] = h2{(_Float16)r0.y, (_Float16)r1.y};
    }
  }

  // reducer state (threads 0..127 = waves 0,1): unit u = tid
  const int u = tid;
  const bool red = (tid < 128);
  float bia = 0.f, bif_ = 0.f, bic = 0.f, bio = 0.f, cst = 0.f;
  if (red) { bia = bi[u]; bif_ = bf[u]; bic = bc[u]; bio = bo[u]; }

  __syncthreads();  // xrow visible

  // ---- init comb[0]: e_0 | h_0 = 0
  if (red) {
    const float e0 = emb[(size_t)xrow[0] * HH + u];
    comb[0][u] = (_Float16)e0;
    comb[0][128 + u] = (_Float16)0.f;
  }
  __syncthreads();

  const h2 LO = h2{(_Float16)1.f, (_Float16)0.f};
  const h2 HI = h2{(_Float16)0.f, (_Float16)1.f};

  int buf = 0;
  for (int t = 0; t < TT; ++t) {
    // reducers: issue e_{t+1} gather early (L3-resident emb; used in phase 2)
    float e_nf = 0.f;
    if (red) {
      const int tn = (t + 1 < TT) ? t + 1 : TT - 1;
      e_nf = emb[(size_t)xrow[tn] * HH + u];
    }

    // ---- phase 1: partial dots over own 32-k slice (all threads)
    h2 cc[16];
    {
      const _Float16* cp = &comb[buf][32 * w];
#pragma unroll
      for (int c = 0; c < 4; ++c) {
        const f16x8 v = *(const f16x8*)(cp + 8 * c);
        cc[4 * c + 0] = h2{v[0], v[1]};
        cc[4 * c + 1] = h2{v[2], v[3]};
        cc[4 * c + 2] = h2{v[4], v[5]};
        cc[4 * c + 3] = h2{v[6], v[7]};
      }
    }
    float a0[4], a1[4];  // 4 gates for unit 2l, 2l+1
#pragma unroll
    for (int g = 0; g < 4; ++g) {
      float s0 = 0.f, s1 = 0.f;
#pragma unroll
      for (int i = 0; i < 16; ++i) {
        s0 = fdot2(cc[i], wfr[g][0][i], s0);
        s1 = fdot2(cc[i], wfr[g][1][i], s1);
      }
      a0[g] = s0;
      a1[g] = s1;
    }
    {
      H2x4 q;
      q.a = pkrtz(a0[0], a0[1]);  // i,f of unit 2l
      q.b = pkrtz(a0[2], a0[3]);  // c,o of unit 2l
      q.c = pkrtz(a1[0], a1[1]);  // i,f of unit 2l+1
      q.d = pkrtz(a1[2], a1[3]);  // c,o of unit 2l+1
      *(H2x4*)(&part[w][l][0]) = q;
    }
    __syncthreads();  // partials visible

    // ---- phase 2: reduce + activate + state update (waves 0,1)
    if (red) {
      float ai = 0.f, af = 0.f, ac = 0.f, ao = 0.f;
      // unit u's (i,f,c,o) quad lives at f16 offset (u>>1)*8 + 4*(u&1) = 4u
      // within each slice's 512-f16 region: contiguous 8B/lane, conflict-free.
      const _Float16* pb = &part[0][0][0] + (size_t)u * 4;
#pragma unroll
      for (int s = 0; s < 8; ++s) {
        const f16x4 pp = *(const f16x4*)(pb + s * 512);
        const h2 pif = h2{pp[0], pp[1]};
        const h2 pco = h2{pp[2], pp[3]};
        ai = fdot2(pif, LO, ai);
        af = fdot2(pif, HI, af);
        ac = fdot2(pco, LO, ac);
        ao = fdot2(pco, HI, ao);
      }
      const float gi = fsigmoid(ai + bia);
      const float gf = fsigmoid(af + bif_);
      const float gc = ftanh(ac + bic);
      const float go = fsigmoid(ao + bio);
      cst = gf * cst + gi * gc;
      const float hv = go * ftanh(cst);
      comb[buf ^ 1][128 + u] = (_Float16)hv;
      comb[buf ^ 1][u] = (_Float16)e_nf;
      if (t == TT - 1) hbf[(size_t)b * HH + u] = (_Float16)hv;
    }
    __syncthreads();  // comb[buf^1] complete
    buf ^= 1;
  }
}

// Wout[k][v] fp32 -> Wt[v][k] fp16 (coalesced loads across lanes=v).
__global__ __launch_bounds__(256, 4) void wout_tr(const float* __restrict__ Wout,
                                                  _Float16* __restrict__ Wt) {
  const int v = blockIdx.x * 256 + threadIdx.x;
#pragma unroll 1
  for (int kc = 0; kc < 16; ++kc) {
    float f[8];
#pragma unroll
    for (int i = 0; i < 8; ++i) f[i] = Wout[(size_t)(kc * 8 + i) * VV + v];
    H2x4 q;
    q.a = pkrtz(f[0], f[1]);
    q.b = pkrtz(f[2], f[3]);
    q.c = pkrtz(f[4], f[5]);
    q.d = pkrtz(f[6], f[7]);
    *(H2x4*)(Wt + (size_t)v * HH + kc * 8) = q;
  }
}

// logits = h @ Wout + bout via f16 MFMA, register-only.
// Block: 4 waves; tile [64 bat x 128 v]; wave: [64 bat x 32 v].
__global__ __launch_bounds__(256, 4) void lstm_out(
    const _Float16* __restrict__ Wt, const _Float16* __restrict__ hbf,
    const float* __restrict__ bout, float* __restrict__ out) {
  const int tid = threadIdx.x;
  const int wv = tid >> 6;
  const int lane = tid & 63;
  const int vblk = blockIdx.x % 250;
  const int batblk = blockIdx.x / 250;
  const int n16 = lane & 15;
  const int quad = lane >> 4;
  const int vbase = vblk * 128 + wv * 32;
  const int batbase = batblk * 64;

  f32x4 acc[4][2] = {};
#pragma unroll
  for (int ks = 0; ks < 4; ++ks) {
    const int k = ks * 32 + quad * 8;
    f16x8 a[4], bf_[2];
#pragma unroll
    for (int mt = 0; mt < 4; ++mt)
      a[mt] = *(const f16x8*)(hbf + (size_t)(batbase + mt * 16 + n16) * HH + k);
#pragma unroll
    for (int vt = 0; vt < 2; ++vt)
      bf_[vt] = *(const f16x8*)(Wt + (size_t)(vbase + vt * 16 + n16) * HH + k);
#pragma unroll
    for (int mt = 0; mt < 4; ++mt)
#pragma unroll
      for (int vt = 0; vt < 2; ++vt)
        acc[mt][vt] = __builtin_amdgcn_mfma_f32_16x16x32_f16(a[mt], bf_[vt],
                                                             acc[mt][vt], 0, 0, 0);
  }
#pragma unroll
  for (int vt = 0; vt < 2; ++vt) {
    const int v = vbase + vt * 16 + n16;
    const float bv = bout[v];
#pragma unroll
    for (int mt = 0; mt < 4; ++mt) {
#pragma unroll
      for (int r = 0; r < 4; ++r) {
        const int bat = batbase + mt * 16 + quad * 4 + r;
        out[(size_t)bat * VV + v] = acc[mt][vt][r] + bv;
      }
    }
  }
}

extern "C" void kernel_launch(void* const* d_in, const int* in_sizes, int n_in,
                              void* d_out, int out_size, void* d_ws,
                              size_t ws_size, hipStream_t stream) {
  const int* x = (const int*)d_in[0];
  const float* emb = (const float*)d_in[1];
  const float* Wi = (const float*)d_in[2];
  const float* bi = (const float*)d_in[3];
  const float* Wf = (const float*)d_in[4];
  const float* bf = (const float*)d_in[5];
  const float* Wc = (const float*)d_in[6];
  const float* bc = (const float*)d_in[7];
  const float* Wo = (const float*)d_in[8];
  const float* bo = (const float*)d_in[9];
  const float* Wout = (const float*)d_in[10];
  const float* bout = (const float*)d_in[11];
  float* out = (float*)d_out;

  _Float16* Wt = (_Float16*)d_ws;        // 32000*128 f16 = 8.192 MB
  _Float16* hbf = Wt + (size_t)VV * HH;  // 256*128 f16 = 64 KB

  wout_tr<<<VV / 256, 256, 0, stream>>>(Wout, Wt);
  lstm_rec<<<BB, 512, 0, stream>>>(x, emb, Wi, bi, Wf, bf, Wc, bc, Wo, bo, hbf);
  lstm_out<<<(VV / 128) * (BB / 64), 256, 0, stream>>>(Wt, hbf, bout, out);
}